// Round 3
// baseline (306.799 us; speedup 1.0000x reference)
//
#include <hip/hip_runtime.h>
#include <stdint.h>

#define T_TOK 8192
#define DD 1024
#define OO 1024
#define EE 8
#define CAP 8192
#define BM 128
#define BN 256
#define BK 64
#define NKT (DD / BK)

typedef __attribute__((ext_vector_type(8))) short short8;
typedef __attribute__((ext_vector_type(4))) float f32x4;

#define FENCE() asm volatile("" ::: "memory")

__device__ __forceinline__ unsigned short f2b(float f){
  union { float f; unsigned u; } v; v.f = f;
  unsigned r = v.u + 0x7FFFu + ((v.u >> 16) & 1u);
  return (unsigned short)(r >> 16);
}

__device__ __forceinline__ void gld16(const void* g, void* l){
  __builtin_amdgcn_global_load_lds(
      (const __attribute__((address_space(1))) unsigned int*)g,
      (__attribute__((address_space(3))) unsigned int*)l,
      16, 0, 0);
}

// ---------------- expert_w [e][d][o] f32 -> Wt [e][o][d] bf16 ----------------
__global__ __launch_bounds__(256) void transp_kernel(const float* __restrict__ w,
                                                     unsigned short* __restrict__ wt){
  __shared__ float t[32][33];
  const int e = blockIdx.z;
  const int dbase = blockIdx.x * 32;
  const int obase = blockIdx.y * 32;
  const int lx = threadIdx.x & 31, ly = threadIdx.x >> 5;
  const float* src = w + ((size_t)e << 20);
  #pragma unroll
  for (int i = 0; i < 4; ++i){
    int d = dbase + ly + i * 8;
    t[ly + i * 8][lx] = src[(size_t)d * OO + obase + lx];
  }
  __syncthreads();
  unsigned short* dst = wt + ((size_t)e << 20);
  #pragma unroll
  for (int i = 0; i < 4; ++i){
    int o = obase + ly + i * 8;
    dst[(size_t)o * DD + dbase + lx] = f2b(t[lx][ly + i * 8]);
  }
}

// ---------------- router: logits + top-2, no atomics, fused x->bf16 ----------------
__global__ __launch_bounds__(256) void router_kernel(
    const float* __restrict__ x, const float* __restrict__ gw, const float* __restrict__ gb,
    int2* __restrict__ e01, float2* __restrict__ w01, unsigned short* __restrict__ xb)
{
  __shared__ float sgw[EE * DD];
  const int tid = threadIdx.x;
  for (int i = tid; i < EE * DD / 4; i += 256)
    ((float4*)sgw)[i] = ((const float4*)gw)[i];
  __syncthreads();
  const int wid = tid >> 6, l = tid & 63;
  const int t = blockIdx.x * 4 + wid;
  double acc[EE];
  #pragma unroll
  for (int e = 0; e < EE; ++e) acc[e] = 0.0;
  const float4* xr = (const float4*)(x + (size_t)t * DD);
  ushort4* xw = (ushort4*)(xb + (size_t)t * DD);
  #pragma unroll
  for (int it = 0; it < 4; ++it){
    float4 xv = xr[it * 64 + l];
    ushort4 r;
    r.x = f2b(xv.x); r.y = f2b(xv.y); r.z = f2b(xv.z); r.w = f2b(xv.w);
    xw[it * 64 + l] = r;
    #pragma unroll
    for (int e = 0; e < EE; ++e){
      float4 g = ((const float4*)(sgw + e * DD))[it * 64 + l];
      acc[e] += (double)xv.x * g.x + (double)xv.y * g.y
              + (double)xv.z * g.z + (double)xv.w * g.w;
    }
  }
  #pragma unroll
  for (int off = 32; off > 0; off >>= 1){
    #pragma unroll
    for (int e = 0; e < EE; ++e) acc[e] += __shfl_xor(acc[e], off);
  }
  if (l == 0){
    float lg[EE];
    #pragma unroll
    for (int e = 0; e < EE; ++e) lg[e] = (float)acc[e] + gb[e];
    int e0 = 0; float v0 = lg[0];
    for (int e = 1; e < EE; ++e) if (lg[e] > v0){ v0 = lg[e]; e0 = e; }
    int e1 = -1; float v1 = -3.4e38f;
    for (int e = 0; e < EE; ++e) if (e != e0 && lg[e] > v1){ v1 = lg[e]; e1 = e; }
    float ex = expf(v1 - v0);
    float s = 1.0f + ex;
    e01[t] = make_int2(e0, e1);
    w01[t] = make_float2(1.0f / s, ex / s);
  }
}

// ---------------- per-expert compaction (LDS scan, no atomics) ----------------
__global__ __launch_bounds__(256) void compact_kernel(
    const int2* __restrict__ e01, const float2* __restrict__ w01,
    int* __restrict__ counts, int* __restrict__ toks, float* __restrict__ wts)
{
  const int e = blockIdx.x;
  const int tid = threadIdx.x;
  __shared__ int pre[256];
  const int base = tid * (T_TOK / 256);
  int c = 0;
  #pragma unroll 4
  for (int i = 0; i < T_TOK / 256; ++i){
    int2 ee = e01[base + i];
    c += (ee.x == e || ee.y == e) ? 1 : 0;
  }
  pre[tid] = c;
  __syncthreads();
  #pragma unroll
  for (int off = 1; off < 256; off <<= 1){
    int add = (tid >= off) ? pre[tid - off] : 0;
    __syncthreads();
    pre[tid] += add;
    __syncthreads();
  }
  int pos = pre[tid] - c;
  #pragma unroll 4
  for (int i = 0; i < T_TOK / 256; ++i){
    int2 ee = e01[base + i];
    if (ee.x == e || ee.y == e){
      float2 ww = w01[base + i];
      toks[e * CAP + pos] = base + i;
      wts[e * CAP + pos] = (ee.x == e) ? ww.x : ww.y;
      ++pos;
    }
  }
  if (tid == 255) counts[e] = pre[255];
}

// ---------------- worklist: tile descriptors for dynamic scheduling ----------------
__global__ __launch_bounds__(64) void worklist_kernel(const int* __restrict__ counts,
                                                      int* __restrict__ meta,
                                                      int* __restrict__ descs){
  const int l = threadIdx.x;
  int preE[EE]; int total = 0;
  #pragma unroll
  for (int e = 0; e < EE; ++e){ preE[e] = total; total += (counts[e] + BM - 1) / BM; }
  if (l == 0) meta[1] = total * 4;               // 4 n-tiles each (meta[0]=ctr, zeroed by memset)
  for (int g = l; g < total; g += 64){
    int e = 0;
    #pragma unroll
    for (int k = 1; k < EE; ++k) if (preE[k] <= g) e = k;
    int mt = g - preE[e];
    #pragma unroll
    for (int nt = 0; nt < 4; ++nt) descs[g * 4 + nt] = (e << 16) | (mt << 2) | nt;
  }
}

// ---------------- persistent gathered GEMM: 128x256x64, 8 waves, dbuf + counted vmcnt ----
__global__ __launch_bounds__(512, 2) void moe_gemm(
    const unsigned short* __restrict__ xb,
    const unsigned short* __restrict__ wtr,
    const float* __restrict__ ebias,
    const int* __restrict__ counts,
    const int* __restrict__ toks,
    const float* __restrict__ wts,
    const int* __restrict__ descs,
    int* __restrict__ meta,
    float* __restrict__ out)
{
  extern __shared__ unsigned short lds[];   // 2 bufs x (A 8192 + B 16384) shorts = 96 KB
  const int tid = threadIdx.x;
  const int wid = tid >> 6, l = tid & 63;
  const int wr = wid >> 2, wcn = wid & 3;
  const int rA = l & 15, hi = l >> 4, x7 = l & 7;
  const int cswz = (l & 7) ^ (l >> 3);
  const int rloc = wid * 8 + (l >> 3);
  const int ntiles = meta[1];
  __shared__ int s_tile;

  for (;;) {
    __syncthreads();
    if (tid == 0) s_tile = atomicAdd(&meta[0], 1);
    __syncthreads();
    const int t = s_tile;
    if (t >= ntiles) return;
    const int d = descs[t];
    const int nt = d & 3, mt = (d >> 2) & 127, e = d >> 16;
    const int cnt = counts[e];
    const int lb = e * CAP;

    const unsigned short* srcA[2];
    const unsigned short* srcB[4];
    #pragma unroll
    for (int j = 0; j < 2; ++j){
      int gr = mt * BM + j * 64 + rloc; if (gr > cnt - 1) gr = cnt - 1;
      srcA[j] = xb + (size_t)toks[lb + gr] * DD + cswz * 8;
    }
    #pragma unroll
    for (int j = 0; j < 4; ++j)
      srcB[j] = wtr + ((size_t)e << 20) + (size_t)(nt * BN + j * 64 + rloc) * DD + cswz * 8;

    // bias values loaded pre-loop (drained by first counted wait; never mid-loop)
    const int col0 = nt * BN + wcn * 64;
    float bvals[4];
    #pragma unroll
    for (int nn = 0; nn < 4; ++nn) bvals[nn] = ebias[e * OO + col0 + nn * 16 + rA];

    f32x4 acc[4][4];
    #pragma unroll
    for (int m = 0; m < 4; ++m)
      #pragma unroll
      for (int n = 0; n < 4; ++n) acc[m][n] = (f32x4)0.0f;

    // stage K-tile 0 -> buf 0
    #pragma unroll
    for (int j = 0; j < 2; ++j)
      gld16(srcA[j], lds + ((size_t)(j * 64 + wid * 8) * 64));
    #pragma unroll
    for (int j = 0; j < 4; ++j)
      gld16(srcB[j], lds + 8192 + ((size_t)(j * 64 + wid * 8) * 64));

    for (int kb = 0; kb < NKT; ++kb) {
      const int p = kb & 1;
      if (kb < NKT - 1) {
        unsigned short* bufn = lds + (p ^ 1) * 24576;
        const int ko = (kb + 1) * BK;
        #pragma unroll
        for (int j = 0; j < 2; ++j)
          gld16(srcA[j] + ko, bufn + (j * 64 + wid * 8) * 64);
        #pragma unroll
        for (int j = 0; j < 4; ++j)
          gld16(srcB[j] + ko, bufn + 8192 + (j * 64 + wid * 8) * 64);
        asm volatile("s_waitcnt vmcnt(6)" ::: "memory");   // my 6 older loads landed
      } else {
        asm volatile("s_waitcnt vmcnt(0)" ::: "memory");
      }
      __builtin_amdgcn_s_barrier();                        // everyone's tile-kb data in LDS
      FENCE();
      const unsigned short* A0 = lds + p * 24576;
      const unsigned short* B0 = A0 + 8192;
      short8 af[4][2], bf[2][2];
      #pragma unroll
      for (int mm = 0; mm < 4; ++mm){
        int row = wr * 64 + mm * 16 + rA;
        #pragma unroll
        for (int kk = 0; kk < 2; ++kk)
          af[mm][kk] = *(const short8*)(A0 + row * 64 + ((((kk << 2) + hi) ^ x7) << 3));
      }
      #pragma unroll
      for (int nn = 0; nn < 2; ++nn){
        int row = wcn * 64 + nn * 16 + rA;
        #pragma unroll
        for (int kk = 0; kk < 2; ++kk)
          bf[nn][kk] = *(const short8*)(B0 + row * 64 + ((((kk << 2) + hi) ^ x7) << 3));
      }
      __builtin_amdgcn_s_setprio(1);
      #pragma unroll
      for (int kk = 0; kk < 2; ++kk)
        #pragma unroll
        for (int mm = 0; mm < 4; ++mm)
          #pragma unroll
          for (int nn = 0; nn < 2; ++nn)
            acc[mm][nn] = __builtin_amdgcn_mfma_f32_16x16x32_bf16(af[mm][kk], bf[nn][kk], acc[mm][nn], 0, 0, 0);
      __builtin_amdgcn_s_setprio(0);
      #pragma unroll
      for (int nn = 0; nn < 2; ++nn){
        int row = wcn * 64 + (nn + 2) * 16 + rA;
        #pragma unroll
        for (int kk = 0; kk < 2; ++kk)
          bf[nn][kk] = *(const short8*)(B0 + row * 64 + ((((kk << 2) + hi) ^ x7) << 3));
      }
      __builtin_amdgcn_s_setprio(1);
      #pragma unroll
      for (int kk = 0; kk < 2; ++kk)
        #pragma unroll
        for (int mm = 0; mm < 4; ++mm)
          #pragma unroll
          for (int nn = 0; nn < 2; ++nn)
            acc[mm][nn + 2] = __builtin_amdgcn_mfma_f32_16x16x32_bf16(af[mm][kk], bf[nn][kk], acc[mm][nn + 2], 0, 0, 0);
      __builtin_amdgcn_s_setprio(0);
      FENCE();
      __builtin_amdgcn_s_barrier();                        // all reads of buf p done
    }

    #pragma unroll
    for (int mm = 0; mm < 4; ++mm){
      int rbase = mt * BM + wr * 64 + mm * 16 + hi * 4;
      #pragma unroll
      for (int j = 0; j < 4; ++j){
        int rr = rbase + j;
        if (rr < cnt){
          int tok = toks[lb + rr];
          float wgt = wts[lb + rr];
          float* orow = out + (size_t)tok * OO;
          #pragma unroll
          for (int nn = 0; nn < 4; ++nn)
            atomicAdd(orow + col0 + nn * 16 + rA, wgt * (acc[mm][nn][j] + bvals[nn]));
        }
      }
    }
  }
}

extern "C" void kernel_launch(void* const* d_in, const int* in_sizes, int n_in,
                              void* d_out, int out_size, void* d_ws, size_t ws_size,
                              hipStream_t stream) {
  const float* x     = (const float*)d_in[0];
  const float* gw    = (const float*)d_in[1];
  const float* gb    = (const float*)d_in[2];
  const float* ew    = (const float*)d_in[3];
  const float* ebias = (const float*)d_in[4];
  float* out = (float*)d_out;
  char* ws = (char*)d_ws;

  int*    counts = (int*)ws;                                   // counts[0..7], meta at +8
  int*    meta   = counts + 8;                                 // [ctr, ntiles]
  int*    toks   = (int*)(ws + 1024);
  float*  wts    = (float*)(ws + 1024 + EE * CAP * 4);
  int2*   e01    = (int2*)(ws + 1024 + 2 * EE * CAP * 4);
  float2* w01    = (float2*)(ws + 1024 + 2 * EE * CAP * 4 + T_TOK * 8);
  int*    descs  = (int*)(ws + 704 * 1024);                    // <= 8 KB
  unsigned short* xb  = (unsigned short*)(ws + (1 << 20));
  unsigned short* wtr = xb + (size_t)T_TOK * DD;

  hipMemsetAsync(d_out, 0, (size_t)T_TOK * OO * sizeof(float), stream);
  hipMemsetAsync(counts, 0, 1024, stream);

  hipFuncSetAttribute((const void*)moe_gemm,
                      hipFuncAttributeMaxDynamicSharedMemorySize, 98304);

  transp_kernel<<<dim3(DD / 32, OO / 32, EE), 256, 0, stream>>>(ew, wtr);
  router_kernel<<<T_TOK / 4, 256, 0, stream>>>(x, gw, gb, e01, w01, xb);
  compact_kernel<<<EE, 256, 0, stream>>>(e01, w01, counts, toks, wts);
  worklist_kernel<<<1, 64, 0, stream>>>(counts, meta, descs);
  moe_gemm<<<256, 512, 98304, stream>>>(xb, wtr, ebias, counts, toks, wts,
                                        descs, meta, out);
}

// Round 4
// 165.551 us; speedup vs baseline: 1.8532x; 1.8532x over previous
//
#include <hip/hip_runtime.h>
#include <stdint.h>

#define T_TOK 8192
#define DD 1024
#define OO 1024
#define EE 8
#define CAP 8192
#define BM 128
#define BN 128
#define BK 64
#define NKT (DD / BK)

typedef __attribute__((ext_vector_type(8))) short short8;
typedef __attribute__((ext_vector_type(4))) float f32x4;

#define CFENCE() asm volatile("" ::: "memory")

__device__ __forceinline__ unsigned short f2b(float f){
  union { float f; unsigned u; } v; v.f = f;
  unsigned r = v.u + 0x7FFFu + ((v.u >> 16) & 1u);
  return (unsigned short)(r >> 16);
}

__device__ __forceinline__ void gld16(const void* g, void* l){
  __builtin_amdgcn_global_load_lds(
      (const __attribute__((address_space(1))) unsigned int*)g,
      (__attribute__((address_space(3))) unsigned int*)l,
      16, 0, 0);
}

// ---------------- expert_w [e][d][o] f32 -> Wt [e][o][d] bf16 ----------------
__global__ __launch_bounds__(256) void transp_kernel(const float* __restrict__ w,
                                                     unsigned short* __restrict__ wt){
  __shared__ float t[32][33];
  const int e = blockIdx.z;
  const int dbase = blockIdx.x * 32;
  const int obase = blockIdx.y * 32;
  const int lx = threadIdx.x & 31, ly = threadIdx.x >> 5;
  const float* src = w + ((size_t)e << 20);
  #pragma unroll
  for (int i = 0; i < 4; ++i){
    int d = dbase + ly + i * 8;
    t[ly + i * 8][lx] = src[(size_t)d * OO + obase + lx];
  }
  __syncthreads();
  unsigned short* dst = wt + ((size_t)e << 20);
  #pragma unroll
  for (int i = 0; i < 4; ++i){
    int o = obase + ly + i * 8;
    dst[(size_t)o * DD + dbase + lx] = f2b(t[lx][ly + i * 8]);
  }
}

// ---------------- router: logits + top-2, no atomics, fused x->bf16 ----------------
__global__ __launch_bounds__(256) void router_kernel(
    const float* __restrict__ x, const float* __restrict__ gw, const float* __restrict__ gb,
    int2* __restrict__ e01, float2* __restrict__ w01, unsigned short* __restrict__ xb)
{
  __shared__ float sgw[EE * DD];
  const int tid = threadIdx.x;
  for (int i = tid; i < EE * DD / 4; i += 256)
    ((float4*)sgw)[i] = ((const float4*)gw)[i];
  __syncthreads();
  const int wid = tid >> 6, l = tid & 63;
  const int t = blockIdx.x * 4 + wid;
  double acc[EE];
  #pragma unroll
  for (int e = 0; e < EE; ++e) acc[e] = 0.0;
  const float4* xr = (const float4*)(x + (size_t)t * DD);
  ushort4* xw = (ushort4*)(xb + (size_t)t * DD);
  #pragma unroll
  for (int it = 0; it < 4; ++it){
    float4 xv = xr[it * 64 + l];
    ushort4 r;
    r.x = f2b(xv.x); r.y = f2b(xv.y); r.z = f2b(xv.z); r.w = f2b(xv.w);
    xw[it * 64 + l] = r;
    #pragma unroll
    for (int e = 0; e < EE; ++e){
      float4 g = ((const float4*)(sgw + e * DD))[it * 64 + l];
      acc[e] += (double)xv.x * g.x + (double)xv.y * g.y
              + (double)xv.z * g.z + (double)xv.w * g.w;
    }
  }
  #pragma unroll
  for (int off = 32; off > 0; off >>= 1){
    #pragma unroll
    for (int e = 0; e < EE; ++e) acc[e] += __shfl_xor(acc[e], off);
  }
  if (l == 0){
    float lg[EE];
    #pragma unroll
    for (int e = 0; e < EE; ++e) lg[e] = (float)acc[e] + gb[e];
    int e0 = 0; float v0 = lg[0];
    for (int e = 1; e < EE; ++e) if (lg[e] > v0){ v0 = lg[e]; e0 = e; }
    int e1 = -1; float v1 = -3.4e38f;
    for (int e = 0; e < EE; ++e) if (e != e0 && lg[e] > v1){ v1 = lg[e]; e1 = e; }
    float ex = expf(v1 - v0);
    float s = 1.0f + ex;
    e01[t] = make_int2(e0, e1);
    w01[t] = make_float2(1.0f / s, ex / s);
  }
}

// ---------------- per-expert compaction (LDS scan, no atomics) ----------------
__global__ __launch_bounds__(256) void compact_kernel(
    const int2* __restrict__ e01, const float2* __restrict__ w01,
    int* __restrict__ counts, int* __restrict__ toks, float* __restrict__ wts)
{
  const int e = blockIdx.x;
  const int tid = threadIdx.x;
  __shared__ int pre[256];
  const int base = tid * (T_TOK / 256);
  int c = 0;
  #pragma unroll 4
  for (int i = 0; i < T_TOK / 256; ++i){
    int2 ee = e01[base + i];
    c += (ee.x == e || ee.y == e) ? 1 : 0;
  }
  pre[tid] = c;
  __syncthreads();
  #pragma unroll
  for (int off = 1; off < 256; off <<= 1){
    int add = (tid >= off) ? pre[tid - off] : 0;
    __syncthreads();
    pre[tid] += add;
    __syncthreads();
  }
  int pos = pre[tid] - c;
  #pragma unroll 4
  for (int i = 0; i < T_TOK / 256; ++i){
    int2 ee = e01[base + i];
    if (ee.x == e || ee.y == e){
      float2 ww = w01[base + i];
      toks[e * CAP + pos] = base + i;
      wts[e * CAP + pos] = (ee.x == e) ? ww.x : ww.y;
      ++pos;
    }
  }
  if (tid == 255) counts[e] = pre[255];
}

// ---------------- gathered GEMM: round-2 structure + LDS double-buffer/counted vmcnt ----
// grid: (nt=8, mt=64, e=8); block 256 (4 waves, 2x2 of 64x64); 64 KB LDS -> 2 blocks/CU
__global__ __launch_bounds__(256, 2) void moe_gemm(
    const unsigned short* __restrict__ xb,
    const unsigned short* __restrict__ wtr,
    const float* __restrict__ ebias,
    const int* __restrict__ counts,
    const int* __restrict__ toks,
    const float* __restrict__ wts,
    float* __restrict__ out)
{
  const int e = blockIdx.z;
  const int cnt = counts[e];
  const int mt = blockIdx.y;
  if (mt * BM >= cnt) return;
  const int nt = blockIdx.x;

  __shared__ __align__(16) unsigned short As[2][BM * BK];
  __shared__ __align__(16) unsigned short Bs[2][BN * BK];

  const int tid = threadIdx.x;
  const int wid = tid >> 6;
  const int l = tid & 63;
  const int lb = e * CAP;

  const unsigned short* srcA[4];
  const unsigned short* srcB[4];
  #pragma unroll
  for (int i = 0; i < 4; ++i){
    int r = i * 32 + wid * 8 + (l >> 3);
    int c = (l & 7) ^ (r & 7);
    int gr = mt * BM + r; if (gr > cnt - 1) gr = cnt - 1;
    int tok = toks[lb + gr];
    srcA[i] = xb + (size_t)tok * DD + c * 8;
    srcB[i] = wtr + ((size_t)e << 20) + (size_t)(nt * BN + r) * DD + c * 8;
  }

  const int wr = wid >> 1, wc = wid & 1;
  const int rA = l & 15, hi = l >> 4, x7 = l & 7;

  // bias preloaded; in-order completion drains it before first counted wait
  const int col0 = nt * BN + wc * 64;
  float bvals[4];
  #pragma unroll
  for (int n = 0; n < 4; ++n) bvals[n] = ebias[e * OO + col0 + n * 16 + rA];

  f32x4 acc[4][4];
  #pragma unroll
  for (int m = 0; m < 4; ++m)
    #pragma unroll
    for (int n = 0; n < 4; ++n) acc[m][n] = (f32x4)0.0f;

  // prologue: stage K-tile 0 -> buf 0  (8 loads/wave)
  #pragma unroll
  for (int i = 0; i < 4; ++i){
    gld16(srcA[i], &As[0][(i * 32 + wid * 8) * BK]);
    gld16(srcB[i], &Bs[0][(i * 32 + wid * 8) * BK]);
  }

  for (int kb = 0; kb < NKT; ++kb){
    const int p = kb & 1;
    if (kb < NKT - 1){
      const int ko = (kb + 1) * BK;
      #pragma unroll
      for (int i = 0; i < 4; ++i){
        gld16(srcA[i] + ko, &As[p ^ 1][(i * 32 + wid * 8) * BK]);
        gld16(srcB[i] + ko, &Bs[p ^ 1][(i * 32 + wid * 8) * BK]);
      }
      asm volatile("s_waitcnt vmcnt(8)" ::: "memory");  // my 8 tile-kb loads landed
    } else {
      asm volatile("s_waitcnt vmcnt(0)" ::: "memory");
    }
    __builtin_amdgcn_s_barrier();                       // all waves' tile-kb data in LDS
    CFENCE();
    const char* AsB = (const char*)As[p];
    const char* BsB = (const char*)Bs[p];
    #pragma unroll
    for (int kk = 0; kk < 2; ++kk){
      short8 af[4], bf[4];
      const int ch = ((kk << 2) + hi) ^ x7;
      #pragma unroll
      for (int m = 0; m < 4; ++m){
        int row = wr * 64 + m * 16 + rA;
        af[m] = *(const short8*)(AsB + row * (BK * 2) + ch * 16);
      }
      #pragma unroll
      for (int n = 0; n < 4; ++n){
        int orow = wc * 64 + n * 16 + rA;
        bf[n] = *(const short8*)(BsB + orow * (BK * 2) + ch * 16);
      }
      __builtin_amdgcn_s_setprio(1);
      #pragma unroll
      for (int m = 0; m < 4; ++m)
        #pragma unroll
        for (int n = 0; n < 4; ++n)
          acc[m][n] = __builtin_amdgcn_mfma_f32_16x16x32_bf16(af[m], bf[n], acc[m][n], 0, 0, 0);
      __builtin_amdgcn_s_setprio(0);
    }
    CFENCE();
    __builtin_amdgcn_s_barrier();                       // reads of buf p done -> safe to overwrite
  }

  // epilogue: out[tok][col] += w * (acc + bias)
  #pragma unroll
  for (int m = 0; m < 4; ++m){
    int rbase = mt * BM + wr * 64 + m * 16 + hi * 4;
    #pragma unroll
    for (int j = 0; j < 4; ++j){
      int rr = rbase + j;
      if (rr < cnt){
        int tok = toks[lb + rr];
        float wgt = wts[lb + rr];
        float* orow = out + (size_t)tok * OO;
        #pragma unroll
        for (int n = 0; n < 4; ++n)
          atomicAdd(orow + col0 + n * 16 + rA, wgt * (acc[m][n][j] + bvals[n]));
      }
    }
  }
}

extern "C" void kernel_launch(void* const* d_in, const int* in_sizes, int n_in,
                              void* d_out, int out_size, void* d_ws, size_t ws_size,
                              hipStream_t stream) {
  const float* x     = (const float*)d_in[0];
  const float* gw    = (const float*)d_in[1];
  const float* gb    = (const float*)d_in[2];
  const float* ew    = (const float*)d_in[3];
  const float* ebias = (const float*)d_in[4];
  float* out = (float*)d_out;
  char* ws = (char*)d_ws;

  int*    counts = (int*)ws;
  int*    toks   = (int*)(ws + 1024);
  float*  wts    = (float*)(ws + 1024 + EE * CAP * 4);
  int2*   e01    = (int2*)(ws + 1024 + 2 * EE * CAP * 4);
  float2* w01    = (float2*)(ws + 1024 + 2 * EE * CAP * 4 + T_TOK * 8);
  unsigned short* xb  = (unsigned short*)(ws + (1 << 20));
  unsigned short* wtr = xb + (size_t)T_TOK * DD;

  hipMemsetAsync(d_out, 0, (size_t)T_TOK * OO * sizeof(float), stream);

  transp_kernel<<<dim3(DD / 32, OO / 32, EE), 256, 0, stream>>>(ew, wtr);
  router_kernel<<<T_TOK / 4, 256, 0, stream>>>(x, gw, gb, e01, w01, xb);
  compact_kernel<<<EE, 256, 0, stream>>>(e01, w01, counts, toks, wts);
  moe_gemm<<<dim3(OO / BN, T_TOK / BM, EE), 256, 0, stream>>>(xb, wtr, ebias,
                                                              counts, toks, wts, out);
}

// Round 6
// 149.946 us; speedup vs baseline: 2.0461x; 1.1041x over previous
//
#include <hip/hip_runtime.h>
#include <stdint.h>

#define T_TOK 8192
#define DD 1024
#define OO 1024
#define EE 8
#define CAP 8192
#define BM 128
#define BN 128
#define BK 64

typedef __attribute__((ext_vector_type(8))) short short8;
typedef __attribute__((ext_vector_type(4))) float f32x4;

__device__ __forceinline__ unsigned short f2b(float f){
  union { float f; unsigned u; } v; v.f = f;
  unsigned r = v.u + 0x7FFFu + ((v.u >> 16) & 1u);
  return (unsigned short)(r >> 16);
}

__device__ __forceinline__ void gld16(const void* g, void* l){
  __builtin_amdgcn_global_load_lds(
      (const __attribute__((address_space(1))) unsigned int*)g,
      (__attribute__((address_space(3))) unsigned int*)l,
      16, 0, 0);
}

// ---------------- phase 0b: expert_w [e][d][o] f32 -> Wt [e][o][d] bf16 ----------------
__global__ __launch_bounds__(256) void transp_kernel(const float* __restrict__ w,
                                                     unsigned short* __restrict__ wt){
  __shared__ float t[32][33];
  const int e = blockIdx.z;
  const int dbase = blockIdx.x * 32;
  const int obase = blockIdx.y * 32;
  const int lx = threadIdx.x & 31, ly = threadIdx.x >> 5;   // 32 x 8
  const float* src = w + ((size_t)e << 20);
  #pragma unroll
  for (int i = 0; i < 4; ++i){
    int d = dbase + ly + i * 8;
    t[ly + i * 8][lx] = src[(size_t)d * OO + obase + lx];
  }
  __syncthreads();
  unsigned short* dst = wt + ((size_t)e << 20);
  #pragma unroll
  for (int i = 0; i < 4; ++i){
    int o = obase + ly + i * 8;
    dst[(size_t)o * DD + dbase + lx] = f2b(t[lx][ly + i * 8]);
  }
}

// ---------------- phase 1a: router logits + top-2 (NO atomics) + fused x->bf16 ----------------
__global__ __launch_bounds__(256) void router_kernel(
    const float* __restrict__ x, const float* __restrict__ gw, const float* __restrict__ gb,
    int2* __restrict__ e01, float2* __restrict__ w01, unsigned short* __restrict__ xb)
{
  __shared__ float sgw[EE * DD];
  const int tid = threadIdx.x;
  for (int i = tid; i < EE * DD / 4; i += 256)
    ((float4*)sgw)[i] = ((const float4*)gw)[i];
  __syncthreads();
  const int wid = tid >> 6, l = tid & 63;
  const int t = blockIdx.x * 4 + wid;
  double acc[EE];
  #pragma unroll
  for (int e = 0; e < EE; ++e) acc[e] = 0.0;
  const float4* xr = (const float4*)(x + (size_t)t * DD);
  ushort4* xw = (ushort4*)(xb + (size_t)t * DD);
  #pragma unroll
  for (int it = 0; it < 4; ++it){
    float4 xv = xr[it * 64 + l];
    ushort4 r;
    r.x = f2b(xv.x); r.y = f2b(xv.y); r.z = f2b(xv.z); r.w = f2b(xv.w);
    xw[it * 64 + l] = r;                         // fused x -> bf16
    #pragma unroll
    for (int e = 0; e < EE; ++e){
      float4 g = ((const float4*)(sgw + e * DD))[it * 64 + l];
      acc[e] += (double)xv.x * g.x + (double)xv.y * g.y
              + (double)xv.z * g.z + (double)xv.w * g.w;
    }
  }
  #pragma unroll
  for (int off = 32; off > 0; off >>= 1){
    #pragma unroll
    for (int e = 0; e < EE; ++e) acc[e] += __shfl_xor(acc[e], off);
  }
  if (l == 0){
    float lg[EE];
    #pragma unroll
    for (int e = 0; e < EE; ++e) lg[e] = (float)acc[e] + gb[e];
    int e0 = 0; float v0 = lg[0];
    for (int e = 1; e < EE; ++e) if (lg[e] > v0){ v0 = lg[e]; e0 = e; }
    int e1 = -1; float v1 = -3.4e38f;
    for (int e = 0; e < EE; ++e) if (e != e0 && lg[e] > v1){ v1 = lg[e]; e1 = e; }
    float ex = expf(v1 - v0);            // <= 1
    float s = 1.0f + ex;
    e01[t] = make_int2(e0, e1);
    w01[t] = make_float2(1.0f / s, ex / s);
  }
}

// ---------------- phase 1b: per-expert compaction (8 blocks, LDS scan, no atomics) ------
__global__ __launch_bounds__(256) void compact_kernel(
    const int2* __restrict__ e01, const float2* __restrict__ w01,
    int* __restrict__ counts, int* __restrict__ toks, float* __restrict__ wts)
{
  const int e = blockIdx.x;
  const int tid = threadIdx.x;
  __shared__ int pre[256];
  const int base = tid * (T_TOK / 256);          // 32 tokens/thread, token-ordered
  int c = 0;
  #pragma unroll 4
  for (int i = 0; i < T_TOK / 256; ++i){
    int2 ee = e01[base + i];
    c += (ee.x == e || ee.y == e) ? 1 : 0;
  }
  pre[tid] = c;
  __syncthreads();
  #pragma unroll
  for (int off = 1; off < 256; off <<= 1){
    int add = (tid >= off) ? pre[tid - off] : 0;
    __syncthreads();
    pre[tid] += add;
    __syncthreads();
  }
  int pos = pre[tid] - c;                        // exclusive prefix
  #pragma unroll 4
  for (int i = 0; i < T_TOK / 256; ++i){
    int2 ee = e01[base + i];
    if (ee.x == e || ee.y == e){
      float2 ww = w01[base + i];
      toks[e * CAP + pos] = base + i;
      wts[e * CAP + pos] = (ee.x == e) ? ww.x : ww.y;
      ++pos;
    }
  }
  if (tid == 255) counts[e] = pre[255];
}

// ---------------- phase 2: per-expert gathered GEMM ----------------
// grid: (nt=OO/BN=8, mt=64, e=8); block 256 (4 waves, 2x2 of 64x64)
// launch_bounds(256,4): cap combined VGPR+AGPR at 128/wave -> 4 blocks/CU target
__global__ __launch_bounds__(256, 4) void moe_gemm(
    const unsigned short* __restrict__ xb,     // [T][D] bf16
    const unsigned short* __restrict__ wtr,    // [E][O][D] bf16 (pre-transposed)
    const float* __restrict__ ebias,           // [E][O]
    const int* __restrict__ counts,
    const int* __restrict__ toks,
    const float* __restrict__ wts,
    float* __restrict__ out)                   // [T][O] f32, pre-zeroed
{
  const int e = blockIdx.z;
  const int cnt = counts[e];
  const int mt = blockIdx.y;
  if (mt * BM >= cnt) return;
  const int nt = blockIdx.x;

  __shared__ __align__(16) unsigned short As[BM * BK];  // rows=tokens, 128B row, chunk-swizzled
  __shared__ __align__(16) unsigned short Bs[BN * BK];  // rows=o,      128B row, chunk-swizzled

  const int tid = threadIdx.x;
  const int wid = tid >> 6;
  const int l = tid & 63;
  const int lb = e * CAP;

  // staging: per thread 4 (row, chunk) pairs for A and B; pre-swizzled SOURCE chunk
  const unsigned short* srcA[4];
  const unsigned short* srcB[4];
  #pragma unroll
  for (int i = 0; i < 4; ++i){
    int r = i * 32 + wid * 8 + (l >> 3);          // tile row 0..127
    int c = (l & 7) ^ (r & 7);                    // logical k-chunk for this physical slot
    int gr = mt * BM + r; if (gr > cnt - 1) gr = cnt - 1;
    int tok = toks[lb + gr];
    srcA[i] = xb + (size_t)tok * DD + c * 8;
    srcB[i] = wtr + ((size_t)e << 20) + (size_t)(nt * BN + r) * DD + c * 8;
  }

  f32x4 acc[4][4];
  #pragma unroll
  for (int m = 0; m < 4; ++m)
    #pragma unroll
    for (int n = 0; n < 4; ++n) acc[m][n] = (f32x4)0.0f;

  const int wr = wid >> 1, wc = wid & 1;
  const int rA = l & 15, hi = l >> 4, x7 = l & 7;
  const char* AsB = (const char*)As;
  const char* BsB = (const char*)Bs;

  for (int kb = 0; kb < DD / BK; ++kb){
    __syncthreads();                              // previous compute done
    #pragma unroll
    for (int i = 0; i < 4; ++i){
      gld16(srcA[i] + kb * BK, As + (i * 32 + wid * 8) * BK);
      gld16(srcB[i] + kb * BK, Bs + (i * 32 + wid * 8) * BK);
    }
    __syncthreads();                              // drains vmcnt before barrier
    #pragma unroll
    for (int kk = 0; kk < 2; ++kk){
      short8 af[4], bf[4];
      const int ch = ((kk << 2) + hi) ^ x7;       // swizzled read chunk
      #pragma unroll
      for (int m = 0; m < 4; ++m){
        int row = wr * 64 + m * 16 + rA;          // row&7 == l&7
        af[m] = *(const short8*)(AsB + row * (BK * 2) + ch * 16);
      }
      #pragma unroll
      for (int n = 0; n < 4; ++n){
        int orow = wc * 64 + n * 16 + rA;
        bf[n] = *(const short8*)(BsB + orow * (BK * 2) + ch * 16);
      }
      #pragma unroll
      for (int m = 0; m < 4; ++m)
        #pragma unroll
        for (int n = 0; n < 4; ++n)
          acc[m][n] = __builtin_amdgcn_mfma_f32_16x16x32_bf16(af[m], bf[n], acc[m][n], 0, 0, 0);
    }
  }

  // epilogue: out[tok][col] += w * (acc + bias)
  const int col0 = nt * BN + wc * 64;
  float bvals[4];
  #pragma unroll
  for (int n = 0; n < 4; ++n) bvals[n] = ebias[e * OO + col0 + n * 16 + rA];
  #pragma unroll
  for (int m = 0; m < 4; ++m){
    int rbase = mt * BM + wr * 64 + m * 16 + hi * 4;
    #pragma unroll
    for (int j = 0; j < 4; ++j){
      int rr = rbase + j;
      if (rr < cnt){
        int tok = toks[lb + rr];
        float wgt = wts[lb + rr];
        float* orow = out + (size_t)tok * OO;
        #pragma unroll
        for (int n = 0; n < 4; ++n)
          atomicAdd(orow + col0 + n * 16 + rA, wgt * (acc[m][n][j] + bvals[n]));
      }
    }
  }
}

extern "C" void kernel_launch(void* const* d_in, const int* in_sizes, int n_in,
                              void* d_out, int out_size, void* d_ws, size_t ws_size,
                              hipStream_t stream) {
  const float* x     = (const float*)d_in[0];
  const float* gw    = (const float*)d_in[1];
  const float* gb    = (const float*)d_in[2];
  const float* ew    = (const float*)d_in[3];
  const float* ebias = (const float*)d_in[4];
  float* out = (float*)d_out;
  char* ws = (char*)d_ws;

  int*    counts = (int*)ws;                                   // 1 KB reserved
  int*    toks   = (int*)(ws + 1024);                          // 256 KB
  float*  wts    = (float*)(ws + 1024 + EE * CAP * 4);         // 256 KB
  int2*   e01    = (int2*)(ws + 1024 + 2 * EE * CAP * 4);      // 64 KB
  float2* w01    = (float2*)(ws + 1024 + 2 * EE * CAP * 4 + T_TOK * 8); // 64 KB
  unsigned short* xb  = (unsigned short*)(ws + (1 << 20));     // 16 MB
  unsigned short* wtr = xb + (size_t)T_TOK * DD;               // 16 MB

  hipMemsetAsync(d_out, 0, (size_t)T_TOK * OO * sizeof(float), stream);

  transp_kernel<<<dim3(DD / 32, OO / 32, EE), 256, 0, stream>>>(ew, wtr);
  router_kernel<<<T_TOK / 4, 256, 0, stream>>>(x, gw, gb, e01, w01, xb);
  compact_kernel<<<EE, 256, 0, stream>>>(e01, w01, counts, toks, wts);
  moe_gemm<<<dim3(OO / BN, T_TOK / BM, EE), 256, 0, stream>>>(xb, wtr, ebias,
                                                              counts, toks, wts, out);
}